// Round 6
// baseline (863.283 us; speedup 1.0000x reference)
//
#include <hip/hip_runtime.h>
#include <hip/hip_bf16.h>
#include <stdint.h>

#define D 128
#define LAYERS 5
#define BN_EPS 1e-5f

typedef unsigned int uint32;
typedef __bf16 bf16x8 __attribute__((ext_vector_type(8)));
typedef float f32x4 __attribute__((ext_vector_type(4)));
typedef float f32x2 __attribute__((ext_vector_type(2)));

// fp32 -> bf16 bits, round-to-nearest-even
__device__ inline unsigned short f2bf(float f) {
    uint32 u = __float_as_uint(f);
    return (unsigned short)((u + 0x7fffu + ((u >> 16) & 1u)) >> 16);
}
__device__ inline float bflo(uint32 p) { return __uint_as_float(p << 16); }
__device__ inline float bfhi(uint32 p) { return __uint_as_float(p & 0xffff0000u); }
__device__ inline uint32 pack2(float a, float b) {
    return (uint32)f2bf(a) | ((uint32)f2bf(b) << 16);
}

// ---------------- edge_index layout detection ----------------

__global__ void detect_kernel(const int* __restrict__ ei, int* __restrict__ flag) {
    if (threadIdx.x == 0 && blockIdx.x == 0) {
        int allz = 1;
#pragma unroll
        for (int i = 0; i < 16; ++i) allz &= (ei[2 * i + 1] == 0);
        *flag = allz;  // 1 => int64 layout, 0 => int32 layout
    }
}

// ---------------- CSR build (dst -> incoming edges) ----------------

__global__ __launch_bounds__(256) void hist_kernel(const int* __restrict__ ei,
                                                   const int* __restrict__ flag,
                                                   int* __restrict__ deg, int E, int n) {
    int e = blockIdx.x * blockDim.x + threadIdx.x;
    if (e >= E) return;
    int is64 = *flag;
    int d = is64 ? ei[2 * ((size_t)E + e)] : ei[E + e];
    if ((unsigned)d < (unsigned)n) atomicAdd(&deg[d], 1);
}

__global__ __launch_bounds__(1024) void scan_kernel(const int* __restrict__ deg,
                                                    int* __restrict__ off, int n) {
    __shared__ int tsum[1024];
    int t = threadIdx.x;
    int CH = (n + 1023) >> 10;
    int lo = t * CH;
    int hi = lo + CH; if (hi > n) hi = n;
    int s = 0;
    for (int i = lo; i < hi; ++i) s += deg[i];
    tsum[t] = s;
    __syncthreads();
    for (int d = 1; d < 1024; d <<= 1) {
        int v = (t >= d) ? tsum[t - d] : 0;
        __syncthreads();
        tsum[t] += v;
        __syncthreads();
    }
    int run = tsum[t] - s;  // exclusive prefix
    for (int i = lo; i < hi; ++i) { off[i] = run; run += deg[i]; }
    if (t == 1023) off[n] = tsum[1023];
}

__global__ __launch_bounds__(256) void fill_kernel(const int* __restrict__ ei,
                                                   const int* __restrict__ flag,
                                                   const int* __restrict__ off,
                                                   int* __restrict__ cursor,
                                                   int* __restrict__ srcs,
                                                   int* __restrict__ eidx, int E, int n) {
    int e = blockIdx.x * blockDim.x + threadIdx.x;
    if (e >= E) return;
    int is64 = *flag;
    int d = is64 ? ei[2 * ((size_t)E + e)] : ei[E + e];
    int s = is64 ? ei[2 * (size_t)e] : ei[e];
    if ((unsigned)d >= (unsigned)n || (unsigned)s >= (unsigned)n) return;
    int p = atomicAdd(&cursor[d], 1);
    int pos = off[d] + p;
    srcs[pos] = s;
    eidx[pos] = e;
}

// ---------------- W -> Wt bf16 transpose-convert: wt[l][n][k] = bf16(W[l][k][n]) ----

__global__ __launch_bounds__(256) void wt_kernel(const float* __restrict__ W1,
                                                 const float* __restrict__ W2,
                                                 unsigned short* __restrict__ wt) {
    int id = blockIdx.x * 256 + threadIdx.x;
    if (id >= 10 * 16384) return;
    int l = id >> 14;
    int rem = id & 16383;
    int nn = rem >> 7, kk = rem & 127;
    const float* base = (l < 5) ? (W1 + (size_t)l * 16384) : (W2 + (size_t)(l - 5) * 16384);
    wt[(size_t)l * 16384 + nn * 128 + kk] = f2bf(base[kk * 128 + nn]);
}

// ---------------- FUSED agg + gemm1 (MODE1) --------------------------------------
// Phase 1 (agg): wave wv aggregates nodes r0+wv*16 .. +15 into LDS (bf16 pairs).
//   out_lds[i] = h[i] + sum_j relu(h[src]+eab)   (L0: fp32 x/ea, also writes eab)
// Phase 2 (gemm1): A-fragments read from LDS; out = A @ Wt + b1 (bf16), plus
//   column sum/sumsq of the fp32 outputs atomically added to colstats (BN stats).
// LDS A-tile row stride = 68 uint32 (272B = 17*16B): keeps ds_read_b128 aligned,
// spreads the 16-rows-same-column read across banks (2-way aliasing = free).

template <bool L0>
__global__ __launch_bounds__(256) void fused_kernel(const void* __restrict__ hin,
                                                    const float* __restrict__ ea,
                                                    const int* __restrict__ eidx,
                                                    const uint32* __restrict__ eab,
                                                    uint32* __restrict__ eab_w,
                                                    const int* __restrict__ off,
                                                    const int* __restrict__ srcs,
                                                    const uint4* __restrict__ Wt4,
                                                    const float* __restrict__ bias,
                                                    uint32* __restrict__ outT,
                                                    float* __restrict__ colstats, int n) {
    __shared__ uint32 Asm[64 * 68];
    __shared__ float red[256];
    const int t = threadIdx.x;
    const int wv = t >> 6, lane = t & 63;
    const int r0 = blockIdx.x * 64;
    red[t] = 0.f;

    // ---- phase 1: aggregate 16 nodes per wave ----
    for (int i = 0; i < 16; ++i) {
        const int node = r0 + wv * 16 + i;
        float2 acc = make_float2(0.f, 0.f);
        if (node < n) {
            int e = off[node], end = off[node + 1];
            if (L0) {
                const float* x = (const float*)hin;
                const int c = lane * 2;
                acc = *(const float2*)(x + (size_t)node * D + c);
                for (; e + 4 <= end; e += 4) {
                    int s0 = srcs[e], s1 = srcs[e + 1], s2 = srcs[e + 2], s3 = srcs[e + 3];
                    int y0 = eidx[e], y1 = eidx[e + 1], y2 = eidx[e + 2], y3 = eidx[e + 3];
                    f32x2 v0 = __builtin_nontemporal_load((const f32x2*)(ea + (size_t)y0 * D + c));
                    f32x2 v1 = __builtin_nontemporal_load((const f32x2*)(ea + (size_t)y1 * D + c));
                    f32x2 v2 = __builtin_nontemporal_load((const f32x2*)(ea + (size_t)y2 * D + c));
                    f32x2 v3 = __builtin_nontemporal_load((const f32x2*)(ea + (size_t)y3 * D + c));
                    float2 h0 = *(const float2*)(x + (size_t)s0 * D + c);
                    float2 h1 = *(const float2*)(x + (size_t)s1 * D + c);
                    float2 h2 = *(const float2*)(x + (size_t)s2 * D + c);
                    float2 h3 = *(const float2*)(x + (size_t)s3 * D + c);
                    acc.x += fmaxf(h0.x + v0.x, 0.f) + fmaxf(h1.x + v1.x, 0.f)
                           + fmaxf(h2.x + v2.x, 0.f) + fmaxf(h3.x + v3.x, 0.f);
                    acc.y += fmaxf(h0.y + v0.y, 0.f) + fmaxf(h1.y + v1.y, 0.f)
                           + fmaxf(h2.y + v2.y, 0.f) + fmaxf(h3.y + v3.y, 0.f);
                    __builtin_nontemporal_store(pack2(v0.x, v0.y), eab_w + (size_t)e * 64 + lane);
                    __builtin_nontemporal_store(pack2(v1.x, v1.y), eab_w + (size_t)(e + 1) * 64 + lane);
                    __builtin_nontemporal_store(pack2(v2.x, v2.y), eab_w + (size_t)(e + 2) * 64 + lane);
                    __builtin_nontemporal_store(pack2(v3.x, v3.y), eab_w + (size_t)(e + 3) * 64 + lane);
                }
                for (; e < end; ++e) {
                    int s0 = srcs[e], y0 = eidx[e];
                    float2 v0 = *(const float2*)(ea + (size_t)y0 * D + c);
                    float2 h0 = *(const float2*)(x + (size_t)s0 * D + c);
                    acc.x += fmaxf(h0.x + v0.x, 0.f);
                    acc.y += fmaxf(h0.y + v0.y, 0.f);
                    eab_w[(size_t)e * 64 + lane] = pack2(v0.x, v0.y);
                }
            } else {
                const uint32* h = (const uint32*)hin;
                uint32 hn = h[(size_t)node * 64 + lane];
                acc = make_float2(bflo(hn), bfhi(hn));
                for (; e + 4 <= end; e += 4) {
                    int s0 = srcs[e], s1 = srcs[e + 1], s2 = srcs[e + 2], s3 = srcs[e + 3];
                    uint32 a0 = __builtin_nontemporal_load(eab + (size_t)e * 64 + lane);
                    uint32 a1 = __builtin_nontemporal_load(eab + (size_t)(e + 1) * 64 + lane);
                    uint32 a2 = __builtin_nontemporal_load(eab + (size_t)(e + 2) * 64 + lane);
                    uint32 a3 = __builtin_nontemporal_load(eab + (size_t)(e + 3) * 64 + lane);
                    uint32 h0 = h[(size_t)s0 * 64 + lane];
                    uint32 h1 = h[(size_t)s1 * 64 + lane];
                    uint32 h2 = h[(size_t)s2 * 64 + lane];
                    uint32 h3 = h[(size_t)s3 * 64 + lane];
                    acc.x += fmaxf(bflo(h0) + bflo(a0), 0.f) + fmaxf(bflo(h1) + bflo(a1), 0.f)
                           + fmaxf(bflo(h2) + bflo(a2), 0.f) + fmaxf(bflo(h3) + bflo(a3), 0.f);
                    acc.y += fmaxf(bfhi(h0) + bfhi(a0), 0.f) + fmaxf(bfhi(h1) + bfhi(a1), 0.f)
                           + fmaxf(bfhi(h2) + bfhi(a2), 0.f) + fmaxf(bfhi(h3) + bfhi(a3), 0.f);
                }
                for (; e < end; ++e) {
                    int s0 = srcs[e];
                    uint32 a0 = eab[(size_t)e * 64 + lane];
                    uint32 h0 = h[(size_t)s0 * 64 + lane];
                    acc.x += fmaxf(bflo(h0) + bflo(a0), 0.f);
                    acc.y += fmaxf(bfhi(h0) + bfhi(a0), 0.f);
                }
            }
        }
        Asm[(wv * 16 + i) * 68 + lane] = pack2(acc.x, acc.y);
    }
    __syncthreads();

    // ---- phase 2: GEMM from LDS A-tile ----
    const int lrow = lane & 15, lk = lane >> 4;
    bf16x8 af[4];
    const int arl = wv * 16 + lrow;
#pragma unroll
    for (int c = 0; c < 4; ++c) {
        union { uint4 u; bf16x8 v; } bu;
        bu.u = *(const uint4*)&Asm[arl * 68 + (c * 4 + lk) * 4];
        af[c] = bu.v;
    }

    float s[8], s2[8];
#pragma unroll
    for (int n0 = 0; n0 < 8; ++n0) {
        const int wcol = n0 * 16 + lrow;
        f32x4 acc = {0.f, 0.f, 0.f, 0.f};
#pragma unroll
        for (int c = 0; c < 4; ++c) {
            union { uint4 u; bf16x8 v; } bu;
            bu.u = Wt4[wcol * 16 + c * 4 + lk];
            acc = __builtin_amdgcn_mfma_f32_16x16x32_bf16(af[c], bu.v, acc, 0, 0, 0);
        }
        const float bcol = bias[wcol];
        float ls = 0.f, ls2 = 0.f;
#pragma unroll
        for (int r = 0; r < 4; ++r) {
            int row = r0 + wv * 16 + lk * 4 + r;
            float v = acc[r] + bcol;
            if (row < n) {
                outT[(size_t)row * 64 + (wcol >> 1)] =
                    0;  // placeholder overwritten below (avoid partial-word RMW)
                ls += v; ls2 += v * v;
            }
            s[n0] = ls; s2[n0] = ls2;
        }
    }
    // NOTE: bf16 outputs are 2-per-uint32; adjacent wcol pairs live in one word.
    // Rewrite cleanly: recompute and store via 16-bit stores.
#pragma unroll
    for (int n0 = 0; n0 < 8; ++n0) {
        const int wcol = n0 * 16 + lrow;
        f32x4 acc = {0.f, 0.f, 0.f, 0.f};
#pragma unroll
        for (int c = 0; c < 4; ++c) {
            union { uint4 u; bf16x8 v; } bu;
            bu.u = Wt4[wcol * 16 + c * 4 + lk];
            acc = __builtin_amdgcn_mfma_f32_16x16x32_bf16(af[c], bu.v, acc, 0, 0, 0);
        }
        const float bcol = bias[wcol];
        float ls = 0.f, ls2 = 0.f;
        unsigned short* outB = (unsigned short*)outT;
#pragma unroll
        for (int r = 0; r < 4; ++r) {
            int row = r0 + wv * 16 + lk * 4 + r;
            float v = acc[r] + bcol;
            if (row < n) {
                outB[(size_t)row * D + wcol] = f2bf(v);
                ls += v; ls2 += v * v;
            }
        }
        ls  += __shfl_xor(ls, 16);  ls  += __shfl_xor(ls, 32);
        ls2 += __shfl_xor(ls2, 16); ls2 += __shfl_xor(ls2, 32);
        if (lk == 0) {
            atomicAdd(&red[wcol], ls);
            atomicAdd(&red[D + wcol], ls2);
        }
    }
    __syncthreads();
    if (t < 128) {
        atomicAdd(&colstats[t], red[t]);
        atomicAdd(&colstats[D + t], red[D + t]);
    }
}

// ---------------- gemm2: out = relu(BN(A)) @ Wt + bias ---------------------------
// BN scale/shift computed per-block from this layer's colstats slot.

template <bool F32OUT>
__global__ __launch_bounds__(256) void gemm2_kernel(const uint4* __restrict__ A,
                                                    const uint4* __restrict__ Wt4,
                                                    const float* __restrict__ bias,
                                                    void* __restrict__ outp,
                                                    const float* __restrict__ colstats,
                                                    const float* __restrict__ gamma,
                                                    const float* __restrict__ beta,
                                                    float inv_n, int n) {
    __shared__ float red[256];
    const int t = threadIdx.x;
    const int wv = t >> 6, l = t & 63;
    const int lrow = l & 15, lk = l >> 4;
    const int r0 = blockIdx.x * 64 + wv * 16;

    if (t < 128) {
        float mu = colstats[t] * inv_n;
        float var = colstats[128 + t] * inv_n - mu * mu;
        float inv = rsqrtf(var + BN_EPS);
        float sc = gamma[t] * inv;
        red[t] = sc;
        red[128 + t] = beta[t] - mu * sc;
    }
    __syncthreads();

    bf16x8 af[4];
    const int arow = r0 + lrow;
    const bool rowok = arow < n;
#pragma unroll
    for (int c = 0; c < 4; ++c) {
        union { uint4 u; bf16x8 v; uint32 w[4]; } bu;
        bu.u = make_uint4(0u, 0u, 0u, 0u);
        if (rowok) bu.u = A[(size_t)arow * 16 + c * 4 + lk];
        const int kb = c * 32 + lk * 8;
        float xv[8];
#pragma unroll
        for (int i = 0; i < 4; ++i) {
            xv[2 * i]     = bflo(bu.w[i]);
            xv[2 * i + 1] = bfhi(bu.w[i]);
        }
#pragma unroll
        for (int j = 0; j < 8; ++j)
            xv[j] = fmaxf(fmaf(red[kb + j], xv[j], red[128 + kb + j]), 0.f);
#pragma unroll
        for (int i = 0; i < 4; ++i)
            bu.w[i] = pack2(xv[2 * i], xv[2 * i + 1]);
        af[c] = bu.v;
    }

    float* outF = (float*)outp;
    unsigned short* outB = (unsigned short*)outp;
#pragma unroll
    for (int n0 = 0; n0 < 8; ++n0) {
        const int wcol = n0 * 16 + lrow;
        f32x4 acc = {0.f, 0.f, 0.f, 0.f};
#pragma unroll
        for (int c = 0; c < 4; ++c) {
            union { uint4 u; bf16x8 v; } bu;
            bu.u = Wt4[wcol * 16 + c * 4 + lk];
            acc = __builtin_amdgcn_mfma_f32_16x16x32_bf16(af[c], bu.v, acc, 0, 0, 0);
        }
        const float bcol = bias[wcol];
#pragma unroll
        for (int r = 0; r < 4; ++r) {
            int row = r0 + lk * 4 + r;
            float v = acc[r] + bcol;
            if (row < n) {
                if (F32OUT) outF[(size_t)row * D + wcol] = v;
                else        outB[(size_t)row * D + wcol] = f2bf(v);
            }
        }
    }
}

// ---------------- launch ----------------

extern "C" void kernel_launch(void* const* d_in, const int* in_sizes, int n_in,
                              void* d_out, int out_size, void* d_ws, size_t ws_size,
                              hipStream_t stream) {
    const float* x      = (const float*)d_in[0];
    const int*   ei     = (const int*)d_in[1];
    const float* ea     = (const float*)d_in[2];
    const float* W1     = (const float*)d_in[3];
    const float* b1     = (const float*)d_in[4];
    const float* gamma  = (const float*)d_in[5];
    const float* beta   = (const float*)d_in[6];
    const float* W2     = (const float*)d_in[7];
    const float* b2     = (const float*)d_in[8];
    const int N = in_sizes[0] / D;
    const int E = in_sizes[1] / 2;

    char* w = (char*)d_ws;
    auto alloc = [&](size_t bytes) {
        char* p = w;
        w += (bytes + 255) & ~(size_t)255;
        return p;
    };
    int*    off      = (int*)alloc((size_t)(N + 1) * sizeof(int));
    // single zeroed region: deg[N] | cursor[N] | colstats[5*256]
    int*    zbase    = (int*)alloc(((size_t)2 * N + 5 * 256) * sizeof(int));
    int*    deg      = zbase;
    int*    cursor   = zbase + N;
    float*  colstats = (float*)(zbase + 2 * N);
    int*    flag     = (int*)alloc(256);
    unsigned short* wt = (unsigned short*)alloc(10 * 16384 * sizeof(unsigned short));
    int*    srcs     = (int*)alloc((size_t)E * sizeof(int));
    int*    eidx     = (int*)alloc((size_t)E * sizeof(int));
    uint32* eab      = (uint32*)alloc((size_t)E * 64 * sizeof(uint32));
    uint32* T        = (uint32*)alloc((size_t)N * 64 * sizeof(uint32));  // gemm1 out (bf16)
    uint32* H        = (uint32*)alloc((size_t)N * 64 * sizeof(uint32));  // gemm2 out (bf16)

    wt_kernel<<<(10 * 16384 + 255) / 256, 256, 0, stream>>>(W1, W2, wt);
    detect_kernel<<<1, 64, 0, stream>>>(ei, flag);
    hipMemsetAsync(zbase, 0, ((size_t)2 * N + 5 * 256) * sizeof(int), stream);
    hist_kernel<<<(E + 255) / 256, 256, 0, stream>>>(ei, flag, deg, E, N);
    scan_kernel<<<1, 1024, 0, stream>>>(deg, off, N);
    fill_kernel<<<(E + 255) / 256, 256, 0, stream>>>(ei, flag, off, cursor, srcs, eidx, E, N);

    const int gemmBlocks = (N + 63) / 64;
    const float inv_n = 1.0f / (float)N;

    for (int l = 0; l < LAYERS; ++l) {
        float* cst = colstats + l * 256;
        const uint4* wt1 = (const uint4*)(wt + (size_t)l * 16384);
        const uint4* wt2 = (const uint4*)(wt + (size_t)(5 + l) * 16384);
        if (l == 0)
            fused_kernel<true><<<gemmBlocks, 256, 0, stream>>>(
                x, ea, eidx, nullptr, eab, off, srcs, wt1, b1 + l * D, T, cst, N);
        else
            fused_kernel<false><<<gemmBlocks, 256, 0, stream>>>(
                H, nullptr, nullptr, eab, nullptr, off, srcs, wt1, b1 + l * D, T, cst, N);
        if (l < LAYERS - 1)
            gemm2_kernel<false><<<gemmBlocks, 256, 0, stream>>>(
                (const uint4*)T, wt2, b2 + l * D, H, cst,
                gamma + l * D, beta + l * D, inv_n, N);
        else
            gemm2_kernel<true><<<gemmBlocks, 256, 0, stream>>>(
                (const uint4*)T, wt2, b2 + l * D, d_out, cst,
                gamma + l * D, beta + l * D, inv_n, N);
    }
}

// Round 7
// 849.288 us; speedup vs baseline: 1.0165x; 1.0165x over previous
//
#include <hip/hip_runtime.h>
#include <hip/hip_bf16.h>
#include <stdint.h>

#define D 128
#define LAYERS 5
#define BN_EPS 1e-5f

typedef unsigned int uint32;
typedef __bf16 bf16x8 __attribute__((ext_vector_type(8)));
typedef float f32x4 __attribute__((ext_vector_type(4)));
typedef float f32x2 __attribute__((ext_vector_type(2)));

// fp32 -> bf16 bits, round-to-nearest-even
__device__ inline unsigned short f2bf(float f) {
    uint32 u = __float_as_uint(f);
    return (unsigned short)((u + 0x7fffu + ((u >> 16) & 1u)) >> 16);
}
__device__ inline float bflo(uint32 p) { return __uint_as_float(p << 16); }
__device__ inline float bfhi(uint32 p) { return __uint_as_float(p & 0xffff0000u); }
__device__ inline uint32 pack2(float a, float b) {
    return (uint32)f2bf(a) | ((uint32)f2bf(b) << 16);
}

// ---------------- edge_index layout detection ----------------

__global__ void detect_kernel(const int* __restrict__ ei, int* __restrict__ flag) {
    if (threadIdx.x == 0 && blockIdx.x == 0) {
        int allz = 1;
#pragma unroll
        for (int i = 0; i < 16; ++i) allz &= (ei[2 * i + 1] == 0);
        *flag = allz;  // 1 => int64 layout, 0 => int32 layout
    }
}

// ---------------- CSR build (dst -> incoming edges) ----------------

__global__ __launch_bounds__(256) void hist_kernel(const int* __restrict__ ei,
                                                   const int* __restrict__ flag,
                                                   int* __restrict__ deg, int E, int n) {
    int e = blockIdx.x * blockDim.x + threadIdx.x;
    if (e >= E) return;
    int is64 = *flag;
    int d = is64 ? ei[2 * ((size_t)E + e)] : ei[E + e];
    if ((unsigned)d < (unsigned)n) atomicAdd(&deg[d], 1);
}

__global__ __launch_bounds__(1024) void scan_kernel(const int* __restrict__ deg,
                                                    int* __restrict__ off, int n) {
    __shared__ int tsum[1024];
    int t = threadIdx.x;
    int CH = (n + 1023) >> 10;
    int lo = t * CH;
    int hi = lo + CH; if (hi > n) hi = n;
    int s = 0;
    for (int i = lo; i < hi; ++i) s += deg[i];
    tsum[t] = s;
    __syncthreads();
    for (int d = 1; d < 1024; d <<= 1) {
        int v = (t >= d) ? tsum[t - d] : 0;
        __syncthreads();
        tsum[t] += v;
        __syncthreads();
    }
    int run = tsum[t] - s;  // exclusive prefix
    for (int i = lo; i < hi; ++i) { off[i] = run; run += deg[i]; }
    if (t == 1023) off[n] = tsum[1023];
}

__global__ __launch_bounds__(256) void fill_kernel(const int* __restrict__ ei,
                                                   const int* __restrict__ flag,
                                                   const int* __restrict__ off,
                                                   int* __restrict__ cursor,
                                                   int* __restrict__ srcs,
                                                   int* __restrict__ eidx, int E, int n) {
    int e = blockIdx.x * blockDim.x + threadIdx.x;
    if (e >= E) return;
    int is64 = *flag;
    int d = is64 ? ei[2 * ((size_t)E + e)] : ei[E + e];
    int s = is64 ? ei[2 * (size_t)e] : ei[e];
    if ((unsigned)d >= (unsigned)n || (unsigned)s >= (unsigned)n) return;
    int p = atomicAdd(&cursor[d], 1);
    int pos = off[d] + p;
    srcs[pos] = s;
    eidx[pos] = e;
}

// ---------------- W -> Wt bf16 transpose-convert: wt[l][n][k] = bf16(W[l][k][n]) ----

__global__ __launch_bounds__(256) void wt_kernel(const float* __restrict__ W1,
                                                 const float* __restrict__ W2,
                                                 unsigned short* __restrict__ wt) {
    int id = blockIdx.x * 256 + threadIdx.x;
    if (id >= 10 * 16384) return;
    int l = id >> 14;
    int rem = id & 16383;
    int nn = rem >> 7, kk = rem & 127;
    const float* base = (l < 5) ? (W1 + (size_t)l * 16384) : (W2 + (size_t)(l - 5) * 16384);
    wt[(size_t)l * 16384 + nn * 128 + kk] = f2bf(base[kk * 128 + nn]);
}

// ---------------- x -> bf16 convert (streaming) ----------------

__global__ __launch_bounds__(256) void xb_kernel(const float* __restrict__ x,
                                                 uint32* __restrict__ xb, int total) {
    int i = blockIdx.x * 256 + threadIdx.x;
    if (i >= total) return;
    f32x2 v = *(const f32x2*)(x + 2 * (size_t)i);
    xb[i] = pack2(v.x, v.y);
}

// ---------------- edge-attr -> bf16, CSR-permuted (edge-parallel, 2 edges/wave) ----
// eab[p] = bf16(ea[eidx[p]]).  One wave handles 2 edges: massive TLP, BW-bound.

__global__ __launch_bounds__(256) void cvt_kernel(const float* __restrict__ ea,
                                                  const int* __restrict__ eidx,
                                                  uint32* __restrict__ eab, int E) {
    int wid = ((blockIdx.x * 256 + threadIdx.x) >> 6) * 2;
    int lane = threadIdx.x & 63;
    if (wid >= E) return;
    int y0 = eidx[wid];
    f32x2 v0 = __builtin_nontemporal_load((const f32x2*)(ea + (size_t)y0 * D + lane * 2));
    if (wid + 1 < E) {
        int y1 = eidx[wid + 1];
        f32x2 v1 = __builtin_nontemporal_load((const f32x2*)(ea + (size_t)y1 * D + lane * 2));
        __builtin_nontemporal_store(pack2(v0.x, v0.y), eab + (size_t)wid * 64 + lane);
        __builtin_nontemporal_store(pack2(v1.x, v1.y), eab + (size_t)(wid + 1) * 64 + lane);
    } else {
        __builtin_nontemporal_store(pack2(v0.x, v0.y), eab + (size_t)wid * 64 + lane);
    }
}

// ---------------- aggregate: bf16 h, bf16 ea (CSR-sequential), unroll x4 ----------

__global__ __launch_bounds__(256) void agg_kernel(const uint32* __restrict__ h,
                                                  const uint32* __restrict__ eab,
                                                  const int* __restrict__ off,
                                                  const int* __restrict__ srcs,
                                                  uint32* __restrict__ out, int n) {
    int node = blockIdx.x * 4 + (threadIdx.x >> 6);
    if (node >= n) return;
    int lane = threadIdx.x & 63;
    uint32 hn = h[(size_t)node * 64 + lane];
    float2 acc = make_float2(bflo(hn), bfhi(hn));
    int e = off[node], end = off[node + 1];
    for (; e + 4 <= end; e += 4) {
        int s0 = srcs[e], s1 = srcs[e + 1], s2 = srcs[e + 2], s3 = srcs[e + 3];
        uint32 a0 = __builtin_nontemporal_load(eab + (size_t)e * 64 + lane);
        uint32 a1 = __builtin_nontemporal_load(eab + (size_t)(e + 1) * 64 + lane);
        uint32 a2 = __builtin_nontemporal_load(eab + (size_t)(e + 2) * 64 + lane);
        uint32 a3 = __builtin_nontemporal_load(eab + (size_t)(e + 3) * 64 + lane);
        uint32 h0 = h[(size_t)s0 * 64 + lane];
        uint32 h1 = h[(size_t)s1 * 64 + lane];
        uint32 h2 = h[(size_t)s2 * 64 + lane];
        uint32 h3 = h[(size_t)s3 * 64 + lane];
        acc.x += fmaxf(bflo(h0) + bflo(a0), 0.f) + fmaxf(bflo(h1) + bflo(a1), 0.f)
               + fmaxf(bflo(h2) + bflo(a2), 0.f) + fmaxf(bflo(h3) + bflo(a3), 0.f);
        acc.y += fmaxf(bfhi(h0) + bfhi(a0), 0.f) + fmaxf(bfhi(h1) + bfhi(a1), 0.f)
               + fmaxf(bfhi(h2) + bfhi(a2), 0.f) + fmaxf(bfhi(h3) + bfhi(a3), 0.f);
    }
    for (; e < end; ++e) {
        int s0 = srcs[e];
        uint32 a0 = eab[(size_t)e * 64 + lane];
        uint32 h0 = h[(size_t)s0 * 64 + lane];
        acc.x += fmaxf(bflo(h0) + bflo(a0), 0.f);
        acc.y += fmaxf(bfhi(h0) + bfhi(a0), 0.f);
    }
    out[(size_t)node * 64 + lane] = pack2(acc.x, acc.y);
}

// ---------------- MFMA GEMM: out[N,128] = f(A)[N,128] @ W[128,128] + bias ----------
// A is bf16 [N][128]. MODE 1: f=id, accumulate col sum/sumsq of fp32 output into
// colstats. MODE 2: f(x)=relu(sc[k]*x+sh[k]) with sc/sh computed in-block from
// colstats/gamma/beta (BN folded). F32OUT: write fp32 (final layer) else bf16.
// 256 thr = 4 waves; wave w -> rows blockIdx*64 + w*16; loop 8 col-tiles of 16.
// mfma_f32_16x16x32_bf16: A row=l&15, k=8*(l>>4)+j; B col=l&15; D row=(l>>4)*4+r.

template <int MODE, bool F32OUT>
__global__ __launch_bounds__(256) void gemm_kernel(const uint4* __restrict__ A,
                                                   const uint4* __restrict__ Wt4,
                                                   const float* __restrict__ bias,
                                                   void* __restrict__ outp,
                                                   float* __restrict__ colstats,
                                                   const float* __restrict__ gamma,
                                                   const float* __restrict__ beta,
                                                   float inv_n, int n) {
    __shared__ float red[256];
    const int t = threadIdx.x;
    const int wv = t >> 6, l = t & 63;
    const int lrow = l & 15, lk = l >> 4;
    const int r0 = blockIdx.x * 64 + wv * 16;

    if (MODE == 1) {
        red[t] = 0.f;
    } else {
        if (t < 128) {
            float mu = colstats[t] * inv_n;
            float var = colstats[128 + t] * inv_n - mu * mu;
            float inv = rsqrtf(var + BN_EPS);
            float sc = gamma[t] * inv;
            red[t] = sc;
            red[128 + t] = beta[t] - mu * sc;
        }
    }
    __syncthreads();

    // A fragments for the wave's 16 rows, all K=128 (4 chunks of 32)
    bf16x8 af[4];
    const int arow = r0 + lrow;
    const bool rowok = arow < n;
#pragma unroll
    for (int c = 0; c < 4; ++c) {
        union { uint4 u; bf16x8 v; uint32 w[4]; } bu;
        bu.u = make_uint4(0u, 0u, 0u, 0u);
        if (rowok) bu.u = A[(size_t)arow * 16 + c * 4 + lk];
        if (MODE == 2) {
            const int kb = c * 32 + lk * 8;
            float xv[8];
#pragma unroll
            for (int i = 0; i < 4; ++i) {
                xv[2 * i]     = bflo(bu.w[i]);
                xv[2 * i + 1] = bfhi(bu.w[i]);
            }
#pragma unroll
            for (int j = 0; j < 8; ++j)
                xv[j] = fmaxf(fmaf(red[kb + j], xv[j], red[128 + kb + j]), 0.f);
#pragma unroll
            for (int i = 0; i < 4; ++i)
                bu.w[i] = pack2(xv[2 * i], xv[2 * i + 1]);
        }
        af[c] = bu.v;
    }

    float* outF = (float*)outp;
    unsigned short* outB = (unsigned short*)outp;
    float s[8], s2[8];

#pragma unroll
    for (int n0 = 0; n0 < 8; ++n0) {
        const int wcol = n0 * 16 + lrow;
        f32x4 acc = {0.f, 0.f, 0.f, 0.f};
#pragma unroll
        for (int c = 0; c < 4; ++c) {
            union { uint4 u; bf16x8 v; } bu;
            bu.u = Wt4[wcol * 16 + c * 4 + lk];
            acc = __builtin_amdgcn_mfma_f32_16x16x32_bf16(af[c], bu.v, acc, 0, 0, 0);
        }
        const float bcol = bias[wcol];
        float ls = 0.f, ls2 = 0.f;
#pragma unroll
        for (int r = 0; r < 4; ++r) {
            int row = r0 + lk * 4 + r;
            float v = acc[r] + bcol;
            if (row < n) {
                if (F32OUT) outF[(size_t)row * D + wcol] = v;
                else        outB[(size_t)row * D + wcol] = f2bf(v);
                if (MODE == 1) { ls += v; ls2 += v * v; }
            }
        }
        s[n0] = ls; s2[n0] = ls2;
    }

    if (MODE == 1) {
#pragma unroll
        for (int n0 = 0; n0 < 8; ++n0) {
            const int wcol = n0 * 16 + lrow;
            float ls = s[n0], ls2 = s2[n0];
            ls  += __shfl_xor(ls, 16);  ls  += __shfl_xor(ls, 32);
            ls2 += __shfl_xor(ls2, 16); ls2 += __shfl_xor(ls2, 32);
            if (lk == 0) {
                atomicAdd(&red[wcol], ls);
                atomicAdd(&red[D + wcol], ls2);
            }
        }
        __syncthreads();
        if (t < 128) {
            atomicAdd(&colstats[t], red[t]);
            atomicAdd(&colstats[D + t], red[D + t]);
        }
    }
}

// ---------------- launch ----------------

extern "C" void kernel_launch(void* const* d_in, const int* in_sizes, int n_in,
                              void* d_out, int out_size, void* d_ws, size_t ws_size,
                              hipStream_t stream) {
    const float* x      = (const float*)d_in[0];
    const int*   ei     = (const int*)d_in[1];
    const float* ea     = (const float*)d_in[2];
    const float* W1     = (const float*)d_in[3];
    const float* b1     = (const float*)d_in[4];
    const float* gamma  = (const float*)d_in[5];
    const float* beta   = (const float*)d_in[6];
    const float* W2     = (const float*)d_in[7];
    const float* b2     = (const float*)d_in[8];
    const int N = in_sizes[0] / D;
    const int E = in_sizes[1] / 2;

    char* w = (char*)d_ws;
    auto alloc = [&](size_t bytes) {
        char* p = w;
        w += (bytes + 255) & ~(size_t)255;
        return p;
    };
    int*    off      = (int*)alloc((size_t)(N + 1) * sizeof(int));
    // single zeroed region: deg[N] | cursor[N] | colstats[5*256]
    int*    zbase    = (int*)alloc(((size_t)2 * N + 5 * 256) * sizeof(int));
    int*    deg      = zbase;
    int*    cursor   = zbase + N;
    float*  colstats = (float*)(zbase + 2 * N);
    int*    flag     = (int*)alloc(256);
    unsigned short* wt = (unsigned short*)alloc(10 * 16384 * sizeof(unsigned short));
    int*    srcs     = (int*)alloc((size_t)E * sizeof(int));
    int*    eidx     = (int*)alloc((size_t)E * sizeof(int));
    uint32* eab      = (uint32*)alloc((size_t)E * 64 * sizeof(uint32));
    uint32* xb       = (uint32*)alloc((size_t)N * 64 * sizeof(uint32));  // x (bf16)
    uint32* G        = (uint32*)alloc((size_t)N * 64 * sizeof(uint32));  // agg out (bf16)
    uint32* T        = (uint32*)alloc((size_t)N * 64 * sizeof(uint32));  // gemm1 out (bf16)
    uint32* H        = (uint32*)alloc((size_t)N * 64 * sizeof(uint32));  // gemm2 out (bf16)

    wt_kernel<<<(10 * 16384 + 255) / 256, 256, 0, stream>>>(W1, W2, wt);
    detect_kernel<<<1, 64, 0, stream>>>(ei, flag);
    hipMemsetAsync(zbase, 0, ((size_t)2 * N + 5 * 256) * sizeof(int), stream);
    hist_kernel<<<(E + 255) / 256, 256, 0, stream>>>(ei, flag, deg, E, N);
    scan_kernel<<<1, 1024, 0, stream>>>(deg, off, N);
    fill_kernel<<<(E + 255) / 256, 256, 0, stream>>>(ei, flag, off, cursor, srcs, eidx, E, N);
    xb_kernel<<<(N * 64 + 255) / 256, 256, 0, stream>>>(x, xb, N * 64);
    cvt_kernel<<<(E + 7) / 8, 256, 0, stream>>>(ea, eidx, eab, E);

    const int gemmBlocks = (N + 63) / 64;
    const int aggBlocks  = (N + 3) / 4;
    const float inv_n = 1.0f / (float)N;

    const uint32* hin = xb;
    for (int l = 0; l < LAYERS; ++l) {
        float* cst = colstats + l * 256;
        const uint4* wt1 = (const uint4*)(wt + (size_t)l * 16384);
        const uint4* wt2 = (const uint4*)(wt + (size_t)(5 + l) * 16384);
        agg_kernel<<<aggBlocks, 256, 0, stream>>>(hin, eab, off, srcs, G, N);
        gemm_kernel<1, false><<<gemmBlocks, 256, 0, stream>>>(
            (const uint4*)G, wt1, b1 + l * D, T, cst, nullptr, nullptr, inv_n, N);
        if (l < LAYERS - 1)
            gemm_kernel<2, false><<<gemmBlocks, 256, 0, stream>>>(
                (const uint4*)T, wt2, b2 + l * D, H, cst,
                gamma + l * D, beta + l * D, inv_n, N);
        else
            gemm_kernel<2, true><<<gemmBlocks, 256, 0, stream>>>(
                (const uint4*)T, wt2, b2 + l * D, d_out, cst,
                gamma + l * D, beta + l * D, inv_n, N);
        hin = H;
    }
}

// Round 8
// 782.756 us; speedup vs baseline: 1.1029x; 1.0850x over previous
//
#include <hip/hip_runtime.h>
#include <hip/hip_bf16.h>
#include <stdint.h>

#define D 128
#define LAYERS 5
#define BN_EPS 1e-5f

typedef unsigned int uint32;
typedef __bf16 bf16x8 __attribute__((ext_vector_type(8)));
typedef float f32x4 __attribute__((ext_vector_type(4)));
typedef float f32x2 __attribute__((ext_vector_type(2)));
typedef uint32 u32x2 __attribute__((ext_vector_type(2)));
typedef uint32 u32x4 __attribute__((ext_vector_type(4)));

// fp32 -> bf16 bits, round-to-nearest-even
__device__ inline unsigned short f2bf(float f) {
    uint32 u = __float_as_uint(f);
    return (unsigned short)((u + 0x7fffu + ((u >> 16) & 1u)) >> 16);
}
__device__ inline float bflo(uint32 p) { return __uint_as_float(p << 16); }
__device__ inline float bfhi(uint32 p) { return __uint_as_float(p & 0xffff0000u); }
__device__ inline uint32 pack2(float a, float b) {
    return (uint32)f2bf(a) | ((uint32)f2bf(b) << 16);
}

// ---------------- edge_index layout detection ----------------

__global__ void detect_kernel(const int* __restrict__ ei, int* __restrict__ flag) {
    if (threadIdx.x == 0 && blockIdx.x == 0) {
        int allz = 1;
#pragma unroll
        for (int i = 0; i < 16; ++i) allz &= (ei[2 * i + 1] == 0);
        *flag = allz;  // 1 => int64 layout, 0 => int32 layout
    }
}

// ---------------- CSR build (dst -> incoming edges) ----------------

__global__ __launch_bounds__(256) void hist_kernel(const int* __restrict__ ei,
                                                   const int* __restrict__ flag,
                                                   int* __restrict__ deg, int E, int n) {
    int e = blockIdx.x * blockDim.x + threadIdx.x;
    if (e >= E) return;
    int is64 = *flag;
    int d = is64 ? ei[2 * ((size_t)E + e)] : ei[E + e];
    if ((unsigned)d < (unsigned)n) atomicAdd(&deg[d], 1);
}

__global__ __launch_bounds__(1024) void scan_kernel(const int* __restrict__ deg,
                                                    int* __restrict__ off, int n) {
    __shared__ int tsum[1024];
    int t = threadIdx.x;
    int CH = (n + 1023) >> 10;
    int lo = t * CH;
    int hi = lo + CH; if (hi > n) hi = n;
    int s = 0;
    for (int i = lo; i < hi; ++i) s += deg[i];
    tsum[t] = s;
    __syncthreads();
    for (int d = 1; d < 1024; d <<= 1) {
        int v = (t >= d) ? tsum[t - d] : 0;
        __syncthreads();
        tsum[t] += v;
        __syncthreads();
    }
    int run = tsum[t] - s;  // exclusive prefix
    for (int i = lo; i < hi; ++i) { off[i] = run; run += deg[i]; }
    if (t == 1023) off[n] = tsum[1023];
}

__global__ __launch_bounds__(256) void fill_kernel(const int* __restrict__ ei,
                                                   const int* __restrict__ flag,
                                                   const int* __restrict__ off,
                                                   int* __restrict__ cursor,
                                                   int* __restrict__ srcs,
                                                   int* __restrict__ eidx, int E, int n) {
    int e = blockIdx.x * blockDim.x + threadIdx.x;
    if (e >= E) return;
    int is64 = *flag;
    int d = is64 ? ei[2 * ((size_t)E + e)] : ei[E + e];
    int s = is64 ? ei[2 * (size_t)e] : ei[e];
    if ((unsigned)d >= (unsigned)n || (unsigned)s >= (unsigned)n) return;
    int p = atomicAdd(&cursor[d], 1);
    int pos = off[d] + p;
    srcs[pos] = s;
    eidx[pos] = e;
}

// ---------------- W -> Wt bf16 transpose-convert: wt[l][n][k] = bf16(W[l][k][n]) ----

__global__ __launch_bounds__(256) void wt_kernel(const float* __restrict__ W1,
                                                 const float* __restrict__ W2,
                                                 unsigned short* __restrict__ wt) {
    int id = blockIdx.x * 256 + threadIdx.x;
    if (id >= 10 * 16384) return;
    int l = id >> 14;
    int rem = id & 16383;
    int nn = rem >> 7, kk = rem & 127;
    const float* base = (l < 5) ? (W1 + (size_t)l * 16384) : (W2 + (size_t)(l - 5) * 16384);
    wt[(size_t)l * 16384 + nn * 128 + kk] = f2bf(base[kk * 128 + nn]);
}

// ---------------- layer-0 aggregate (fp32 x/ea) fused with ea->bf16 CSR convert ----
// One wave per node. Lane layout: half = lane>>5 picks edge within a 2-edge slot;
// q = lane&31 covers cols 4q..4q+3 (f32x4 = 16B loads). 2 slots unrolled = 4 edges
// in flight, all 16B loads -> 2x in-flight bytes vs the 8B/lane version.

__global__ __launch_bounds__(256) void agg_cvt_kernel(const float* __restrict__ x,
                                                      const float* __restrict__ ea,
                                                      const int* __restrict__ off,
                                                      const int* __restrict__ srcs,
                                                      const int* __restrict__ eidx,
                                                      uint32* __restrict__ eab,
                                                      uint32* __restrict__ out, int n) {
    int node = blockIdx.x * 4 + (threadIdx.x >> 6);
    if (node >= n) return;
    const int lane = threadIdx.x & 63;
    const int half = lane >> 5;
    const int q = lane & 31;
    f32x4 acc = {0.f, 0.f, 0.f, 0.f};
    int e = off[node], end = off[node + 1];
    for (; e + 4 <= end; e += 4) {
        int eA = e + half, eB = e + 2 + half;
        int sA = srcs[eA], sB = srcs[eB];
        int yA = eidx[eA], yB = eidx[eB];
        f32x4 va = __builtin_nontemporal_load((const f32x4*)(ea + (size_t)yA * D + q * 4));
        f32x4 vb = __builtin_nontemporal_load((const f32x4*)(ea + (size_t)yB * D + q * 4));
        f32x4 ha = *(const f32x4*)(x + (size_t)sA * D + q * 4);
        f32x4 hb = *(const f32x4*)(x + (size_t)sB * D + q * 4);
#pragma unroll
        for (int k = 0; k < 4; ++k)
            acc[k] += fmaxf(ha[k] + va[k], 0.f) + fmaxf(hb[k] + vb[k], 0.f);
        u32x2 pa = {pack2(va[0], va[1]), pack2(va[2], va[3])};
        u32x2 pb = {pack2(vb[0], vb[1]), pack2(vb[2], vb[3])};
        __builtin_nontemporal_store(pa, (u32x2*)(eab + (size_t)eA * 64 + q * 2));
        __builtin_nontemporal_store(pb, (u32x2*)(eab + (size_t)eB * 64 + q * 2));
    }
    for (; e < end; ++e) {  // <=3 remaining, half==0 lanes active
        if (half == 0) {
            int s0 = srcs[e], y0 = eidx[e];
            f32x4 v = __builtin_nontemporal_load((const f32x4*)(ea + (size_t)y0 * D + q * 4));
            f32x4 h = *(const f32x4*)(x + (size_t)s0 * D + q * 4);
#pragma unroll
            for (int k = 0; k < 4; ++k) acc[k] += fmaxf(h[k] + v[k], 0.f);
            u32x2 pv = {pack2(v[0], v[1]), pack2(v[2], v[3])};
            __builtin_nontemporal_store(pv, (u32x2*)(eab + (size_t)e * 64 + q * 2));
        }
    }
#pragma unroll
    for (int k = 0; k < 4; ++k) acc[k] += __shfl_xor(acc[k], 32);
    if (half == 0) {
        f32x4 xs = *(const f32x4*)(x + (size_t)node * D + q * 4);
        u32x2 o = {pack2(xs[0] + acc[0], xs[1] + acc[1]),
                   pack2(xs[2] + acc[2], xs[3] + acc[3])};
        *(u32x2*)(out + (size_t)node * 64 + q * 2) = o;
    }
}

// ---------------- aggregate (layers 1+): bf16 h/ea ----------------
// One wave per node. g = lane>>4 picks edge within a 4-edge slot; j = lane&15
// covers cols 8j..8j+7 (u32x4 = 16B loads). 2 slots unrolled = 8 edges in flight.

__global__ __launch_bounds__(256) void agg_kernel(const uint32* __restrict__ h,
                                                  const uint32* __restrict__ eab,
                                                  const int* __restrict__ off,
                                                  const int* __restrict__ srcs,
                                                  uint32* __restrict__ out, int n) {
    int node = blockIdx.x * 4 + (threadIdx.x >> 6);
    if (node >= n) return;
    const int lane = threadIdx.x & 63;
    const int g = lane >> 4;
    const int j = lane & 15;
    float acc[8] = {0.f, 0.f, 0.f, 0.f, 0.f, 0.f, 0.f, 0.f};
    int e = off[node], end = off[node + 1];
    for (; e + 8 <= end; e += 8) {
        int e0 = e + g, e1 = e + 4 + g;
        int s0 = srcs[e0], s1 = srcs[e1];
        u32x4 a0 = __builtin_nontemporal_load((const u32x4*)(eab + (size_t)e0 * 64 + j * 4));
        u32x4 a1 = __builtin_nontemporal_load((const u32x4*)(eab + (size_t)e1 * 64 + j * 4));
        u32x4 h0 = *(const u32x4*)(h + (size_t)s0 * 64 + j * 4);
        u32x4 h1 = *(const u32x4*)(h + (size_t)s1 * 64 + j * 4);
#pragma unroll
        for (int k = 0; k < 4; ++k) {
            acc[2 * k]     += fmaxf(bflo(h0[k]) + bflo(a0[k]), 0.f)
                            + fmaxf(bflo(h1[k]) + bflo(a1[k]), 0.f);
            acc[2 * k + 1] += fmaxf(bfhi(h0[k]) + bfhi(a0[k]), 0.f)
                            + fmaxf(bfhi(h1[k]) + bfhi(a1[k]), 0.f);
        }
    }
    if (e + 4 <= end) {
        int e0 = e + g;
        int s0 = srcs[e0];
        u32x4 a0 = __builtin_nontemporal_load((const u32x4*)(eab + (size_t)e0 * 64 + j * 4));
        u32x4 h0 = *(const u32x4*)(h + (size_t)s0 * 64 + j * 4);
#pragma unroll
        for (int k = 0; k < 4; ++k) {
            acc[2 * k]     += fmaxf(bflo(h0[k]) + bflo(a0[k]), 0.f);
            acc[2 * k + 1] += fmaxf(bfhi(h0[k]) + bfhi(a0[k]), 0.f);
        }
        e += 4;
    }
    for (; e < end; ++e) {  // <=3 remaining, g==0 lanes active
        if (g == 0) {
            int s0 = srcs[e];
            u32x4 a0 = *(const u32x4*)(eab + (size_t)e * 64 + j * 4);
            u32x4 h0 = *(const u32x4*)(h + (size_t)s0 * 64 + j * 4);
#pragma unroll
            for (int k = 0; k < 4; ++k) {
                acc[2 * k]     += fmaxf(bflo(h0[k]) + bflo(a0[k]), 0.f);
                acc[2 * k + 1] += fmaxf(bfhi(h0[k]) + bfhi(a0[k]), 0.f);
            }
        }
    }
#pragma unroll
    for (int k = 0; k < 8; ++k) {
        acc[k] += __shfl_xor(acc[k], 16);
        acc[k] += __shfl_xor(acc[k], 32);
    }
    if (g == 0) {
        u32x4 hn = *(const u32x4*)(h + (size_t)node * 64 + j * 4);
        u32x4 o;
#pragma unroll
        for (int k = 0; k < 4; ++k)
            o[k] = pack2(bflo(hn[k]) + acc[2 * k], bfhi(hn[k]) + acc[2 * k + 1]);
        *(u32x4*)(out + (size_t)node * 64 + j * 4) = o;
    }
}

// ---------------- MFMA GEMM: out[N,128] = f(A)[N,128] @ W[128,128] + bias ----------
// A is bf16 [N][128]. MODE 1: f=id, accumulate col sum/sumsq of fp32 output into
// colstats. MODE 2: f(x)=relu(sc[k]*x+sh[k]) with sc/sh computed in-block from
// colstats/gamma/beta (BN folded). F32OUT: write fp32 (final layer) else bf16.
// mfma_f32_16x16x32_bf16: A row=l&15, k=8*(l>>4)+j; B col=l&15; D row=(l>>4)*4+r.

template <int MODE, bool F32OUT>
__global__ __launch_bounds__(256) void gemm_kernel(const uint4* __restrict__ A,
                                                   const uint4* __restrict__ Wt4,
                                                   const float* __restrict__ bias,
                                                   void* __restrict__ outp,
                                                   float* __restrict__ colstats,
                                                   const float* __restrict__ gamma,
                                                   const float* __restrict__ beta,
                                                   float inv_n, int n) {
    __shared__ float red[256];
    const int t = threadIdx.x;
    const int wv = t >> 6, l = t & 63;
    const int lrow = l & 15, lk = l >> 4;
    const int r0 = blockIdx.x * 64 + wv * 16;

    if (MODE == 1) {
        red[t] = 0.f;
    } else {
        if (t < 128) {
            float mu = colstats[t] * inv_n;
            float var = colstats[128 + t] * inv_n - mu * mu;
            float inv = rsqrtf(var + BN_EPS);
            float sc = gamma[t] * inv;
            red[t] = sc;
            red[128 + t] = beta[t] - mu * sc;
        }
    }
    __syncthreads();

    bf16x8 af[4];
    const int arow = r0 + lrow;
    const bool rowok = arow < n;
#pragma unroll
    for (int c = 0; c < 4; ++c) {
        union { uint4 u; bf16x8 v; uint32 w[4]; } bu;
        bu.u = make_uint4(0u, 0u, 0u, 0u);
        if (rowok) bu.u = A[(size_t)arow * 16 + c * 4 + lk];
        if (MODE == 2) {
            const int kb = c * 32 + lk * 8;
            float xv[8];
#pragma unroll
            for (int i = 0; i < 4; ++i) {
                xv[2 * i]     = bflo(bu.w[i]);
                xv[2 * i + 1] = bfhi(bu.w[i]);
            }
#pragma unroll
            for (int j = 0; j < 8; ++j)
                xv[j] = fmaxf(fmaf(red[kb + j], xv[j], red[128 + kb + j]), 0.f);
#pragma unroll
            for (int i = 0; i < 4; ++i)
                bu.w[i] = pack2(xv[2 * i], xv[2 * i + 1]);
        }
        af[c] = bu.v;
    }

    float* outF = (float*)outp;
    unsigned short* outB = (unsigned short*)outp;
    float s[8], s2[8];

#pragma unroll
    for (int n0 = 0; n0 < 8; ++n0) {
        const int wcol = n0 * 16 + lrow;
        f32x4 acc = {0.f, 0.f, 0.f, 0.f};
#pragma unroll
        for (int c = 0; c < 4; ++c) {
            union { uint4 u; bf16x8 v; } bu;
            bu.u = Wt4[wcol * 16 + c * 4 + lk];
            acc = __builtin_amdgcn_mfma_f32_16x16x32_bf16(af[c], bu.v, acc, 0, 0, 0);
        }
        const float bcol = bias[wcol];
        float ls = 0.f, ls2 = 0.f;
#pragma unroll
        for (int r = 0; r < 4; ++r) {
            int row = r0 + lk * 4 + r;
            float v = acc[r] + bcol;
            if (row < n) {
                if (F32OUT) outF[(size_t)row * D + wcol] = v;
                else        outB[(size_t)row * D + wcol] = f2bf(v);
                if (MODE == 1) { ls += v; ls2 += v * v; }
            }
        }
        s[n0] = ls; s2[n0] = ls2;
    }

    if (MODE == 1) {
#pragma unroll
        for (int n0 = 0; n0 < 8; ++n0) {
            const int wcol = n0 * 16 + lrow;
            float ls = s[n0], ls2 = s2[n0];
            ls  += __shfl_xor(ls, 16);  ls  += __shfl_xor(ls, 32);
            ls2 += __shfl_xor(ls2, 16); ls2 += __shfl_xor(ls2, 32);
            if (lk == 0) {
                atomicAdd(&red[wcol], ls);
                atomicAdd(&red[D + wcol], ls2);
            }
        }
        __syncthreads();
        if (t < 128) {
            atomicAdd(&colstats[t], red[t]);
            atomicAdd(&colstats[D + t], red[D + t]);
        }
    }
}

// ---------------- launch ----------------

extern "C" void kernel_launch(void* const* d_in, const int* in_sizes, int n_in,
                              void* d_out, int out_size, void* d_ws, size_t ws_size,
                              hipStream_t stream) {
    const float* x      = (const float*)d_in[0];
    const int*   ei     = (const int*)d_in[1];
    const float* ea     = (const float*)d_in[2];
    const float* W1     = (const float*)d_in[3];
    const float* b1     = (const float*)d_in[4];
    const float* gamma  = (const float*)d_in[5];
    const float* beta   = (const float*)d_in[6];
    const float* W2     = (const float*)d_in[7];
    const float* b2     = (const float*)d_in[8];
    const int N = in_sizes[0] / D;
    const int E = in_sizes[1] / 2;

    char* w = (char*)d_ws;
    auto alloc = [&](size_t bytes) {
        char* p = w;
        w += (bytes + 255) & ~(size_t)255;
        return p;
    };
    int*    off      = (int*)alloc((size_t)(N + 1) * sizeof(int));
    // single zeroed region: deg[N] | cursor[N] | colstats[5*256]
    int*    zbase    = (int*)alloc(((size_t)2 * N + 5 * 256) * sizeof(int));
    int*    deg      = zbase;
    int*    cursor   = zbase + N;
    float*  colstats = (float*)(zbase + 2 * N);
    int*    flag     = (int*)alloc(256);
    unsigned short* wt = (unsigned short*)alloc(10 * 16384 * sizeof(unsigned short));
    int*    srcs     = (int*)alloc((size_t)E * sizeof(int));
    int*    eidx     = (int*)alloc((size_t)E * sizeof(int));
    uint32* eab      = (uint32*)alloc((size_t)E * 64 * sizeof(uint32));
    uint32* G        = (uint32*)alloc((size_t)N * 64 * sizeof(uint32));  // agg out (bf16)
    uint32* T        = (uint32*)alloc((size_t)N * 64 * sizeof(uint32));  // gemm1 out (bf16)
    uint32* H        = (uint32*)alloc((size_t)N * 64 * sizeof(uint32));  // gemm2 out (bf16)

    wt_kernel<<<(10 * 16384 + 255) / 256, 256, 0, stream>>>(W1, W2, wt);
    detect_kernel<<<1, 64, 0, stream>>>(ei, flag);
    hipMemsetAsync(zbase, 0, ((size_t)2 * N + 5 * 256) * sizeof(int), stream);
    hist_kernel<<<(E + 255) / 256, 256, 0, stream>>>(ei, flag, deg, E, N);
    scan_kernel<<<1, 1024, 0, stream>>>(deg, off, N);
    fill_kernel<<<(E + 255) / 256, 256, 0, stream>>>(ei, flag, off, cursor, srcs, eidx, E, N);

    const int gemmBlocks = (N + 63) / 64;
    const int aggBlocks  = (N + 3) / 4;
    const float inv_n = 1.0f / (float)N;

    const uint32* hin = nullptr;
    for (int l = 0; l < LAYERS; ++l) {
        float* cst = colstats + l * 256;
        const uint4* wt1 = (const uint4*)(wt + (size_t)l * 16384);
        const uint4* wt2 = (const uint4*)(wt + (size_t)(5 + l) * 16384);
        if (l == 0)
            agg_cvt_kernel<<<aggBlocks, 256, 0, stream>>>(x, ea, off, srcs, eidx, eab, G, N);
        else
            agg_kernel<<<aggBlocks, 256, 0, stream>>>(hin, eab, off, srcs, G, N);
        gemm_kernel<1, false><<<gemmBlocks, 256, 0, stream>>>(
            (const uint4*)G, wt1, b1 + l * D, T, cst, nullptr, nullptr, inv_n, N);
        if (l < LAYERS - 1)
            gemm_kernel<2, false><<<gemmBlocks, 256, 0, stream>>>(
                (const uint4*)T, wt2, b2 + l * D, H, cst,
                gamma + l * D, beta + l * D, inv_n, N);
        else
            gemm_kernel<2, true><<<gemmBlocks, 256, 0, stream>>>(
                (const uint4*)T, wt2, b2 + l * D, d_out, cst,
                gamma + l * D, beta + l * D, inv_n, N);
        hin = H;
    }
}